// Round 9
// baseline (456.995 us; speedup 1.0000x reference)
//
#include <hip/hip_runtime.h>
#include <math.h>

// feat_arm/feat_up: [16,144,64,64] f32
// off_w: [144,288,3,3], off_b: [144]
// dcn_w: [256,144,3,3], dcn_b: [256]
// out: [16,256,64,64] f32 (silu)
constexpr int BN = 16;
constexpr int C_IN = 144, C_CAT = 288, C_OFF = 144, C_OUT = 256;
constexpr int OFFG = 8, CG = 18;

constexpr int OFF_ELEMS = BN * C_OFF * 64 * 64;   // fp32 offsets in ws
constexpr int WOFF_PACK = 9 * 9 * 9 * 512;        // 373248 bf16 (cb,tap,mtile,lane,i)
constexpr int WDCN_PACK = 8 * 6 * 16 * 512;       // 393216 bf16 (t=g*6+ks, mtile, lane, i)

typedef __attribute__((ext_vector_type(8))) short bf16x8;
typedef __attribute__((ext_vector_type(4))) float f32x4;

__device__ __forceinline__ unsigned short f2bf(float f) {
  unsigned u = __builtin_bit_cast(unsigned, f);
  return (unsigned short)((u + 0x7FFFu + ((u >> 16) & 1u)) >> 16);  // RNE, finite inputs
}

__device__ __forceinline__ unsigned packh2(float a, float b) {
  unsigned short ha = __builtin_bit_cast(unsigned short, (_Float16)a);
  unsigned short hb = __builtin_bit_cast(unsigned short, (_Float16)b);
  return (unsigned)ha | ((unsigned)hb << 16);
}
__device__ __forceinline__ float h2f_lo(unsigned u) {
  return (float)__builtin_bit_cast(_Float16, (unsigned short)(u & 0xFFFFu));
}
__device__ __forceinline__ float h2f_hi(unsigned u) {
  return (float)__builtin_bit_cast(_Float16, (unsigned short)(u >> 16));
}

// async global->LDS, 16B per lane, wave-uniform LDS base
__device__ __forceinline__ void gload_lds16(const void* g, void* l) {
  __builtin_amdgcn_global_load_lds(
      (const __attribute__((address_space(1))) unsigned*)g,
      (__attribute__((address_space(3))) unsigned*)l, 16, 0, 0);
}

// ---------------------------------------------------------------------------
// Kernel 1: pack both weight tensors into MFMA A-fragment order (bf16).
// A-frag slot (lane, i) of a 16x32 tile: m = lane&15, k = (lane>>4)*8 + i.
// (round-3 proven version)
// ---------------------------------------------------------------------------
__global__ __launch_bounds__(256) void pack_w(
    const float* __restrict__ off_w, const float* __restrict__ dcn_w,
    unsigned short* __restrict__ wo, unsigned short* __restrict__ wd) {
  int idx = blockIdx.x * 256 + threadIdx.x;
  if (idx < WOFF_PACK) {
    int i = idx & 7, lane = (idx >> 3) & 63, t = idx >> 9;
    int mt = t % 9; t /= 9;
    int tap = t % 9, cb = t / 9;
    int co = mt * 16 + (lane & 15);
    int ci = cb * 32 + ((lane >> 4) << 3) + i;
    wo[idx] = f2bf(off_w[(co * C_CAT + ci) * 9 + tap]);
  }
  if (idx < WDCN_PACK) {
    int i = idx & 7, lane = (idx >> 3) & 63, t = idx >> 9;
    int mt = t & 15; t >>= 4;
    int ks = t % 6, g = t / 6;
    int co = mt * 16 + (lane & 15);
    int r = ks * 32 + ((lane >> 4) << 3) + i;
    float v = 0.f;
    if (r < 162) {
      int ci = r / 9, tap = r - ci * 9;
      v = dcn_w[(co * C_IN + g * CG + ci) * 9 + tap];
    }
    wd[idx] = f2bf(v);
  }
}

// ---------------------------------------------------------------------------
// Kernel 2: offset conv via MFMA (9 shifted GEMMs). Identical to round 3.
// ---------------------------------------------------------------------------
__global__ __launch_bounds__(256) void offs_conv_mfma(
    const float* __restrict__ fa, const float* __restrict__ fu,
    const unsigned short* __restrict__ wt, const float* __restrict__ bias,
    float* __restrict__ out) {
  const int b = blockIdx.x >> 5;
  const int y0 = (blockIdx.x & 31) << 1;
  const int tid = threadIdx.x;
  const int wave = tid >> 6, lane = tid & 63;
  const int kg = lane >> 4, ln = lane & 15;

  __shared__ __align__(16) unsigned short xs[4 * 66 * 32];

  f32x4 acc[9][2];
#pragma unroll
  for (int m = 0; m < 9; ++m)
#pragma unroll
    for (int n = 0; n < 2; ++n) acc[m][n] = {0.f, 0.f, 0.f, 0.f};

  for (int cb = 0; cb < 9; ++cb) {
    __syncthreads();
    for (int idx = tid; idx < 2112; idx += 256) {
      int q = idx / 264;
      int rem = idx - q * 264;
      int row = rem / 66;
      int cc = rem - row * 66;
      int y = y0 - 1 + row, x = cc - 1;
      ushort4 wv = make_ushort4(0, 0, 0, 0);
      if (y >= 0 && y < 64 && x >= 0 && x < 64) {
        int cib = cb * 32 + (q << 2);
        const float* p = (cib < C_IN)
                             ? fa + (((size_t)(b * C_IN + cib)) << 12)
                             : fu + (((size_t)(b * C_IN + cib - C_IN)) << 12);
        int o = (y << 6) + x;
        wv.x = f2bf(p[o]);
        wv.y = f2bf(p[o + 4096]);
        wv.z = f2bf(p[o + 8192]);
        wv.w = f2bf(p[o + 12288]);
      }
      int e = ((row * 66 + cc) << 5) + (((q >> 1) ^ (cc & 3)) << 3) + ((q & 1) << 2);
      *(ushort4*)&xs[e] = wv;
    }
    __syncthreads();

    for (int tap = 0; tap < 9; ++tap) {
      const int ky = tap / 3, kx = tap - ky * 3;
      bf16x8 a[9];
      const unsigned short* wp = wt + (((size_t)(cb * 9 + tap) * 9) << 9) + (lane << 3);
#pragma unroll
      for (int m = 0; m < 9; ++m) a[m] = *(const bf16x8*)(wp + (m << 9));
#pragma unroll
      for (int n = 0; n < 2; ++n) {
        int px = ((wave << 1) + n) * 16 + ln;
        int row = (px >> 6) + ky, cc = (px & 63) + kx;
        int e = ((row * 66 + cc) << 5) + ((kg ^ (cc & 3)) << 3);
        bf16x8 bv = *(const bf16x8*)&xs[e];
#pragma unroll
        for (int m = 0; m < 9; ++m)
          acc[m][n] = __builtin_amdgcn_mfma_f32_16x16x32_bf16(a[m], bv, acc[m][n], 0, 0, 0);
      }
    }
  }

#pragma unroll
  for (int n = 0; n < 2; ++n) {
    int px = ((wave << 1) + n) * 16 + ln;
    int y = y0 + (px >> 6), x = px & 63;
#pragma unroll
    for (int m = 0; m < 9; ++m) {
      int cob = m * 16 + (kg << 2);
#pragma unroll
      for (int r = 0; r < 4; ++r)
        out[(((size_t)(b * C_OFF + cob + r)) << 12) + (y << 6) + x] =
            acc[m][n][r] + bias[cob + r];
    }
  }
}

// ---------------------------------------------------------------------------
// Kernel 3: deformable conv via MFMA. Round-7 skeleton (512 thr, 8 waves =
// 2M x 4N, LDS-staged dbuf A). ONE change vs r7: phase-2 gather is a
// BRANCHLESS batch-4 loop over 192 rows (12288 items = 6 x 4 x 512 exact):
// 4 geo ds_reads issued together -> 16 independent global loads in flight
// -> 4 computes/writes. Pad rows (162..191) write 0 via select, loads
// clamped in-bounds. Kills the per-item serial latency chain.
// ---------------------------------------------------------------------------
__global__ __launch_bounds__(512, 4) void dcn_mfma(
    const float* __restrict__ fu, const float* __restrict__ off,
    const unsigned short* __restrict__ wt, const float* __restrict__ bias,
    float* __restrict__ out) {
  const int b = blockIdx.x >> 6, h = blockIdx.x & 63;
  const int tid = threadIdx.x;
  const int wave = tid >> 6, lane = tid & 63;
  const int kg = lane >> 4, ln = lane & 15;
  const int wm = wave >> 2, wn = wave & 3;   // M-half, N-tile
  const int px = (wn << 4) + ln;             // this wave's pixel (n index)

  __shared__ __align__(16) uint4 geo[576];               // [tap*64+px], 9.2KB
  __shared__ __align__(16) unsigned short cols[192 * 66];// [r][px pad 66], 25.3KB
  __shared__ __align__(16) unsigned short wl[2][8192];   // A dbuf, 2x16KB

  f32x4 acc[8];
#pragma unroll
  for (int m = 0; m < 8; ++m) acc[m] = {0.f, 0.f, 0.f, 0.f};

  // prologue: stage A chunk t=0 into buffer 0 (16 rows of 1KB, 2 per wave)
  {
    const unsigned short* src = wt + (wave * 2) * 512 + lane * 8;
#pragma unroll
    for (int j = 0; j < 2; ++j)
      gload_lds16(src + j * 512, &wl[0][(wave * 2 + j) * 512]);
  }

  int t = 0;
  for (int g = 0; g < OFFG; ++g) {
    __syncthreads();  // prev group's cols/geo readers done
    // ---- phase 1: geometry per (tap, px): corner indices + fp16 weights
    for (int idx = tid; idx < 576; idx += 512) {
      int tap = idx >> 6, p = idx & 63;
      int ky = tap / 3, kx = tap - ky * 3;
      int ch = (g * 9 + tap) * 2;
      float oy = off[(((size_t)(b * C_OFF + ch)) << 12) + (h << 6) + p];
      float ox = off[(((size_t)(b * C_OFF + ch + 1)) << 12) + (h << 6) + p];
      float py = (float)(h - 1 + ky) + oy;
      float pxs = (float)(p - 1 + kx) + ox;
      float y0f = floorf(py), x0f = floorf(pxs);
      int y0 = (int)y0f, x0 = (int)x0f;
      float fy = py - y0f, fx = pxs - x0f;
      float vy0 = (y0 >= 0 && y0 < 64) ? 1.f : 0.f;
      float vy1 = (y0 + 1 >= 0 && y0 + 1 < 64) ? 1.f : 0.f;
      float vx0 = (x0 >= 0 && x0 < 64) ? 1.f : 0.f;
      float vx1 = (x0 + 1 >= 0 && x0 + 1 < 64) ? 1.f : 0.f;
      int yc0 = min(max(y0, 0), 63), xc0 = min(max(x0, 0), 63);
      int yc1 = min(max(y0 + 1, 0), 63), xc1 = min(max(x0 + 1, 0), 63);
      uint4 gg;
      gg.x = (unsigned)((yc0 << 6) + xc0) | ((unsigned)((yc0 << 6) + xc1) << 16);
      gg.y = (unsigned)((yc1 << 6) + xc0) | ((unsigned)((yc1 << 6) + xc1) << 16);
      gg.z = packh2((1.f - fy) * (1.f - fx) * vy0 * vx0,
                    (1.f - fy) * fx * vy0 * vx1);
      gg.w = packh2(fy * (1.f - fx) * vy1 * vx0, fy * fx * vy1 * vx1);
      geo[idx] = gg;
    }
    __syncthreads();

    // ---- phase 2: branchless batch-4 gather -> cols[r][px]
    // 192 rows x 64 px = 12288 items = 6 batches x 4 items x 512 threads.
    const float* gbase = fu + (((size_t)(b * C_IN + g * CG)) << 12);
    for (int bt = 0; bt < 6; ++bt) {
      int rr4[4], p4[4];
      uint4 gg4[4];
      const float* pl4[4];
#pragma unroll
      for (int u = 0; u < 4; ++u) {
        int idx = bt * 2048 + u * 512 + tid;
        int rr = idx >> 6, p = idx & 63;     // rr wave-uniform, p = lane
        int ci = rr / 9;
        int tap = rr - ci * 9;               // 0..8 (before clamp)
        ci = ci < CG ? ci : CG - 1;          // clamp pad rows in-bounds
        rr4[u] = rr;
        p4[u] = p;
        gg4[u] = geo[(tap << 6) + p];        // 4 independent ds_read_b128
        pl4[u] = gbase + ((size_t)ci << 12);
      }
      float v4[4][4];
#pragma unroll
      for (int u = 0; u < 4; ++u) {          // 16 independent global loads
        v4[u][0] = pl4[u][gg4[u].x & 0xFFFFu];
        v4[u][1] = pl4[u][gg4[u].x >> 16];
        v4[u][2] = pl4[u][gg4[u].y & 0xFFFFu];
        v4[u][3] = pl4[u][gg4[u].y >> 16];
      }
#pragma unroll
      for (int u = 0; u < 4; ++u) {
        float s = h2f_lo(gg4[u].z) * v4[u][0] + h2f_hi(gg4[u].z) * v4[u][1] +
                  h2f_lo(gg4[u].w) * v4[u][2] + h2f_hi(gg4[u].w) * v4[u][3];
        unsigned short val = (rr4[u] < 162) ? f2bf(s) : (unsigned short)0;
        cols[rr4[u] * 66 + p4[u]] = val;     // stride-1 writes, conflict-free
      }
    }
    __syncthreads();

    // ---- phase 3: 6 MFMA K-steps over this group's 192 (padded) k
    for (int ks = 0; ks < 6; ++ks, ++t) {
      // B fragment: 8 scalar LDS reads (conflict-free via 66-pad)
      bf16x8 bv;
      const unsigned short* cp = &cols[(ks * 32 + (kg << 3)) * 66 + px];
#pragma unroll
      for (int i = 0; i < 8; ++i) bv[i] = (short)cp[i * 66];

      __syncthreads();  // stage(t) drained (vmcnt0); prev buf readers done

      // issue stage(t+1) into the other buffer (2 rows per wave)
      if (t < 47) {
        const unsigned short* src =
            wt + (size_t)(t + 1) * 8192 + (wave * 2) * 512 + lane * 8;
        unsigned short* dst = wl[(t + 1) & 1];
#pragma unroll
        for (int j = 0; j < 2; ++j)
          gload_lds16(src + j * 512, dst + (wave * 2 + j) * 512);
      }

      // 8 MFMAs: this wave's M-half against its B fragment
      const unsigned short* wbuf = wl[t & 1] + (wm * 8) * 512 + lane * 8;
#pragma unroll
      for (int j = 0; j < 8; ++j) {
        bf16x8 av = *(const bf16x8*)(wbuf + j * 512);
        acc[j] = __builtin_amdgcn_mfma_f32_16x16x32_bf16(av, bv, acc[j], 0, 0, 0);
      }
    }
  }

  // ---- epilogue: bias + SiLU.  C/D: col(px)=lane&15, row=kg*4+r
#pragma unroll
  for (int j = 0; j < 8; ++j) {
    int cob = (wm * 8 + j) * 16 + (kg << 2);
#pragma unroll
    for (int r = 0; r < 4; ++r) {
      float y = acc[j][r] + bias[cob + r];
      out[(((size_t)(b * C_OUT + cob + r)) << 12) + (h << 6) + px] =
          y / (1.f + expf(-y));
    }
  }
}

// ---------------------------------------------------------------------------
extern "C" void kernel_launch(void* const* d_in, const int* in_sizes, int n_in,
                              void* d_out, int out_size, void* d_ws, size_t ws_size,
                              hipStream_t stream) {
  const float* feat_arm = (const float*)d_in[0];
  const float* feat_up  = (const float*)d_in[1];
  const float* off_w    = (const float*)d_in[2];
  const float* off_b    = (const float*)d_in[3];
  const float* dcn_w    = (const float*)d_in[4];
  const float* dcn_b    = (const float*)d_in[5];
  float* out = (float*)d_out;

  float* ws = (float*)d_ws;
  float* offbuf = ws;                                        // OFF_ELEMS f32
  unsigned short* wo = (unsigned short*)(ws + OFF_ELEMS);    // WOFF_PACK bf16
  unsigned short* wd = wo + WOFF_PACK;                       // WDCN_PACK bf16

  pack_w<<<(WDCN_PACK + 255) / 256, 256, 0, stream>>>(off_w, dcn_w, wo, wd);
  offs_conv_mfma<<<BN * 32, 256, 0, stream>>>(feat_arm, feat_up, wo, off_b, offbuf);
  dcn_mfma<<<BN * 64, 512, 0, stream>>>(feat_up, offbuf, wd, dcn_b, out);
}

// Round 10
// 365.306 us; speedup vs baseline: 1.2510x; 1.2510x over previous
//
#include <hip/hip_runtime.h>
#include <math.h>

// feat_arm/feat_up: [16,144,64,64] f32
// off_w: [144,288,3,3], off_b: [144]
// dcn_w: [256,144,3,3], dcn_b: [256]
// out: [16,256,64,64] f32 (silu)
constexpr int BN = 16;
constexpr int C_IN = 144, C_CAT = 288, C_OFF = 144, C_OUT = 256;
constexpr int OFFG = 8, CG = 18;

constexpr int OFF_ELEMS = BN * C_OFF * 64 * 64;   // fp32 offsets in ws
constexpr int WOFF_PACK = 9 * 9 * 9 * 512;        // 373248 bf16 (cb,tap,mtile,lane,i)
constexpr int WDCN_PACK = 8 * 6 * 16 * 512;       // 393216 bf16 (t=g*6+ks, mtile, lane, i)

typedef __attribute__((ext_vector_type(8))) short bf16x8;
typedef __attribute__((ext_vector_type(4))) float f32x4;

__device__ __forceinline__ unsigned short f2bf(float f) {
  unsigned u = __builtin_bit_cast(unsigned, f);
  return (unsigned short)((u + 0x7FFFu + ((u >> 16) & 1u)) >> 16);  // RNE, finite inputs
}

__device__ __forceinline__ unsigned packh2(float a, float b) {
  unsigned short ha = __builtin_bit_cast(unsigned short, (_Float16)a);
  unsigned short hb = __builtin_bit_cast(unsigned short, (_Float16)b);
  return (unsigned)ha | ((unsigned)hb << 16);
}
__device__ __forceinline__ float h2f_lo(unsigned u) {
  return (float)__builtin_bit_cast(_Float16, (unsigned short)(u & 0xFFFFu));
}
__device__ __forceinline__ float h2f_hi(unsigned u) {
  return (float)__builtin_bit_cast(_Float16, (unsigned short)(u >> 16));
}

// async global->LDS, 16B per lane, wave-uniform LDS base
__device__ __forceinline__ void gload_lds16(const void* g, void* l) {
  __builtin_amdgcn_global_load_lds(
      (const __attribute__((address_space(1))) unsigned*)g,
      (__attribute__((address_space(3))) unsigned*)l, 16, 0, 0);
}

// ---------------------------------------------------------------------------
// Kernel 1: pack both weight tensors into MFMA A-fragment order (bf16).
// A-frag slot (lane, i) of a 16x32 tile: m = lane&15, k = (lane>>4)*8 + i.
// (round-3 proven version)
// ---------------------------------------------------------------------------
__global__ __launch_bounds__(256) void pack_w(
    const float* __restrict__ off_w, const float* __restrict__ dcn_w,
    unsigned short* __restrict__ wo, unsigned short* __restrict__ wd) {
  int idx = blockIdx.x * 256 + threadIdx.x;
  if (idx < WOFF_PACK) {
    int i = idx & 7, lane = (idx >> 3) & 63, t = idx >> 9;
    int mt = t % 9; t /= 9;
    int tap = t % 9, cb = t / 9;
    int co = mt * 16 + (lane & 15);
    int ci = cb * 32 + ((lane >> 4) << 3) + i;
    wo[idx] = f2bf(off_w[(co * C_CAT + ci) * 9 + tap]);
  }
  if (idx < WDCN_PACK) {
    int i = idx & 7, lane = (idx >> 3) & 63, t = idx >> 9;
    int mt = t & 15; t >>= 4;
    int ks = t % 6, g = t / 6;
    int co = mt * 16 + (lane & 15);
    int r = ks * 32 + ((lane >> 4) << 3) + i;
    float v = 0.f;
    if (r < 162) {
      int ci = r / 9, tap = r - ci * 9;
      v = dcn_w[(co * C_IN + g * CG + ci) * 9 + tap];
    }
    wd[idx] = f2bf(v);
  }
}

// ---------------------------------------------------------------------------
// Kernel 2: offset conv via MFMA (9 shifted GEMMs). Identical to round 3.
// ---------------------------------------------------------------------------
__global__ __launch_bounds__(256) void offs_conv_mfma(
    const float* __restrict__ fa, const float* __restrict__ fu,
    const unsigned short* __restrict__ wt, const float* __restrict__ bias,
    float* __restrict__ out) {
  const int b = blockIdx.x >> 5;
  const int y0 = (blockIdx.x & 31) << 1;
  const int tid = threadIdx.x;
  const int wave = tid >> 6, lane = tid & 63;
  const int kg = lane >> 4, ln = lane & 15;

  __shared__ __align__(16) unsigned short xs[4 * 66 * 32];

  f32x4 acc[9][2];
#pragma unroll
  for (int m = 0; m < 9; ++m)
#pragma unroll
    for (int n = 0; n < 2; ++n) acc[m][n] = {0.f, 0.f, 0.f, 0.f};

  for (int cb = 0; cb < 9; ++cb) {
    __syncthreads();
    for (int idx = tid; idx < 2112; idx += 256) {
      int q = idx / 264;
      int rem = idx - q * 264;
      int row = rem / 66;
      int cc = rem - row * 66;
      int y = y0 - 1 + row, x = cc - 1;
      ushort4 wv = make_ushort4(0, 0, 0, 0);
      if (y >= 0 && y < 64 && x >= 0 && x < 64) {
        int cib = cb * 32 + (q << 2);
        const float* p = (cib < C_IN)
                             ? fa + (((size_t)(b * C_IN + cib)) << 12)
                             : fu + (((size_t)(b * C_IN + cib - C_IN)) << 12);
        int o = (y << 6) + x;
        wv.x = f2bf(p[o]);
        wv.y = f2bf(p[o + 4096]);
        wv.z = f2bf(p[o + 8192]);
        wv.w = f2bf(p[o + 12288]);
      }
      int e = ((row * 66 + cc) << 5) + (((q >> 1) ^ (cc & 3)) << 3) + ((q & 1) << 2);
      *(ushort4*)&xs[e] = wv;
    }
    __syncthreads();

    for (int tap = 0; tap < 9; ++tap) {
      const int ky = tap / 3, kx = tap - ky * 3;
      bf16x8 a[9];
      const unsigned short* wp = wt + (((size_t)(cb * 9 + tap) * 9) << 9) + (lane << 3);
#pragma unroll
      for (int m = 0; m < 9; ++m) a[m] = *(const bf16x8*)(wp + (m << 9));
#pragma unroll
      for (int n = 0; n < 2; ++n) {
        int px = ((wave << 1) + n) * 16 + ln;
        int row = (px >> 6) + ky, cc = (px & 63) + kx;
        int e = ((row * 66 + cc) << 5) + ((kg ^ (cc & 3)) << 3);
        bf16x8 bv = *(const bf16x8*)&xs[e];
#pragma unroll
        for (int m = 0; m < 9; ++m)
          acc[m][n] = __builtin_amdgcn_mfma_f32_16x16x32_bf16(a[m], bv, acc[m][n], 0, 0, 0);
      }
    }
  }

#pragma unroll
  for (int n = 0; n < 2; ++n) {
    int px = ((wave << 1) + n) * 16 + ln;
    int y = y0 + (px >> 6), x = px & 63;
#pragma unroll
    for (int m = 0; m < 9; ++m) {
      int cob = m * 16 + (kg << 2);
#pragma unroll
      for (int r = 0; r < 4; ++r)
        out[(((size_t)(b * C_OFF + cob + r)) << 12) + (y << 6) + x] =
            acc[m][n][r] + bias[cob + r];
    }
  }
}

// ---------------------------------------------------------------------------
// Kernel 3: deformable conv via MFMA. Round-7 skeleton (512 thr, 8 waves =
// 2M x 4N, LDS-staged dbuf A, per-K-step barrier). Gather restructured:
//   - wave w owns tap w; its geometry lives in 4 REGISTERS (computed in
//     phase 1 with lane=px) -> no geo ds_read in the gather chain at all.
//     Tap 8 geometry goes through a 1KB LDS array (one b128 read per wave).
//   - ci-inner loop, batch-3: 12 independent global loads in flight, live
//     state ~24 regs (no spill; r9's batch-4-generic spilled: WRITE 137MB).
//   - cols stored TRANSPOSED colsT[px][200] (400B stride, 16B aligned):
//     phase-3 B-fragment = ONE ds_read_b128 (was 8 ds_read_u16).
// ---------------------------------------------------------------------------
__global__ __launch_bounds__(512, 4) void dcn_mfma(
    const float* __restrict__ fu, const float* __restrict__ off,
    const unsigned short* __restrict__ wt, const float* __restrict__ bias,
    float* __restrict__ out) {
  const int b = blockIdx.x >> 6, h = blockIdx.x & 63;
  const int tid = threadIdx.x;
  const int wave = tid >> 6, lane = tid & 63;
  const int kg = lane >> 4, ln = lane & 15;
  const int wm = wave >> 2, wn = wave & 3;   // M-half, N-tile
  const int px = (wn << 4) + ln;             // this wave's pixel (n index)

  __shared__ __align__(16) uint4 geo8[64];                // tap-8 geo, 1KB
  __shared__ __align__(16) unsigned short colsT[64 * 200];// [px][r pad 200], 25.6KB
  __shared__ __align__(16) unsigned short wl[2][8192];    // A dbuf, 2x16KB

  f32x4 acc[8];
#pragma unroll
  for (int m = 0; m < 8; ++m) acc[m] = {0.f, 0.f, 0.f, 0.f};

  // zero K-pad columns r in [162,200) once (gather never writes them)
  for (int i = tid; i < 64 * 19; i += 512) {
    int p = i / 19, d = i - p * 19;
    *(unsigned*)&colsT[p * 200 + 162 + 2 * d] = 0u;
  }

  // prologue: stage A chunk t=0 into buffer 0 (16 rows of 1KB, 2 per wave)
  {
    const unsigned short* src = wt + (wave * 2) * 512 + lane * 8;
#pragma unroll
    for (int j = 0; j < 2; ++j)
      gload_lds16(src + j * 512, &wl[0][(wave * 2 + j) * 512]);
  }

  // geometry for (group gg, tap, p): packed corner indices + fp16 weights
  auto make_geo = [&](int gg_, int tap, int p) -> uint4 {
    int ky = tap / 3, kx = tap - ky * 3;
    int ch = (gg_ * 9 + tap) * 2;
    float oy = off[(((size_t)(b * C_OFF + ch)) << 12) + (h << 6) + p];
    float ox = off[(((size_t)(b * C_OFF + ch + 1)) << 12) + (h << 6) + p];
    float py = (float)(h - 1 + ky) + oy;
    float pxs = (float)(p - 1 + kx) + ox;
    float y0f = floorf(py), x0f = floorf(pxs);
    int y0 = (int)y0f, x0 = (int)x0f;
    float fy = py - y0f, fx = pxs - x0f;
    float vy0 = (y0 >= 0 && y0 < 64) ? 1.f : 0.f;
    float vy1 = (y0 + 1 >= 0 && y0 + 1 < 64) ? 1.f : 0.f;
    float vx0 = (x0 >= 0 && x0 < 64) ? 1.f : 0.f;
    float vx1 = (x0 + 1 >= 0 && x0 + 1 < 64) ? 1.f : 0.f;
    int yc0 = min(max(y0, 0), 63), xc0 = min(max(x0, 0), 63);
    int yc1 = min(max(y0 + 1, 0), 63), xc1 = min(max(x0 + 1, 0), 63);
    uint4 gg4;
    gg4.x = (unsigned)((yc0 << 6) + xc0) | ((unsigned)((yc0 << 6) + xc1) << 16);
    gg4.y = (unsigned)((yc1 << 6) + xc0) | ((unsigned)((yc1 << 6) + xc1) << 16);
    gg4.z = packh2((1.f - fy) * (1.f - fx) * vy0 * vx0,
                   (1.f - fy) * fx * vy0 * vx1);
    gg4.w = packh2(fy * (1.f - fx) * vy1 * vx0, fy * fx * vy1 * vx1);
    return gg4;
  };

  int t = 0;
  for (int g = 0; g < OFFG; ++g) {
    __syncthreads();  // prev group's colsT + geo8 readers done

    // ---- phase 1: wave w computes tap-w geometry into REGISTERS (p=lane);
    //      wave 0 additionally computes tap 8 -> geo8 LDS.
    uint4 gg = make_geo(g, wave, lane);
    if (wave == 0) geo8[lane] = make_geo(g, 8, lane);
    __syncthreads();

    // ---- phase 2: gather, tap-outer (regs) / ci-inner (batch-3)
    const float* gbase = fu + (((size_t)(b * C_IN + g * CG)) << 12);
    {
      const float w00 = h2f_lo(gg.z), w01 = h2f_hi(gg.z);
      const float w10 = h2f_lo(gg.w), w11 = h2f_hi(gg.w);
      const int i00 = gg.x & 0xFFFFu, i01 = gg.x >> 16;
      const int i10 = gg.y & 0xFFFFu, i11 = gg.y >> 16;
      for (int cb = 0; cb < 18; cb += 3) {
        float v[3][4];
#pragma unroll
        for (int u = 0; u < 3; ++u) {
          const float* pl = gbase + ((size_t)(cb + u) << 12);
          v[u][0] = pl[i00];
          v[u][1] = pl[i01];
          v[u][2] = pl[i10];
          v[u][3] = pl[i11];
        }
#pragma unroll
        for (int u = 0; u < 3; ++u) {
          float s = w00 * v[u][0] + w01 * v[u][1] + w10 * v[u][2] + w11 * v[u][3];
          colsT[lane * 200 + (cb + u) * 9 + wave] = f2bf(s);
        }
      }
      // tap 8 rows: ci8 = wave + 8*j (waves 0,1 -> 3 rows; waves 2..7 -> 2)
      uint4 g8 = geo8[lane];
      const float u00 = h2f_lo(g8.z), u01 = h2f_hi(g8.z);
      const float u10 = h2f_lo(g8.w), u11 = h2f_hi(g8.w);
      const int j00 = g8.x & 0xFFFFu, j01 = g8.x >> 16;
      const int j10 = g8.y & 0xFFFFu, j11 = g8.y >> 16;
      const int n8 = (wave < 2) ? 3 : 2;
      float vv[3][4];
#pragma unroll
      for (int u = 0; u < 3; ++u) {
        if (u < n8) {
          const float* pl = gbase + ((size_t)(wave + 8 * u) << 12);
          vv[u][0] = pl[j00];
          vv[u][1] = pl[j01];
          vv[u][2] = pl[j10];
          vv[u][3] = pl[j11];
        }
      }
#pragma unroll
      for (int u = 0; u < 3; ++u) {
        if (u < n8) {
          float s = u00 * vv[u][0] + u01 * vv[u][1] + u10 * vv[u][2] + u11 * vv[u][3];
          colsT[lane * 200 + (wave + 8 * u) * 9 + 8] = f2bf(s);
        }
      }
    }
    __syncthreads();

    // ---- phase 3: 6 MFMA K-steps over this group's 192 (padded) k
    for (int ks = 0; ks < 6; ++ks, ++t) {
      // B fragment: ONE ds_read_b128 (colsT row-contiguous, 16B aligned)
      bf16x8 bv = *(const bf16x8*)&colsT[px * 200 + ks * 32 + (kg << 3)];

      __syncthreads();  // stage(t) drained (vmcnt0); prev buf readers done

      // issue stage(t+1) into the other buffer (2 rows per wave)
      if (t < 47) {
        const unsigned short* src =
            wt + (size_t)(t + 1) * 8192 + (wave * 2) * 512 + lane * 8;
        unsigned short* dst = wl[(t + 1) & 1];
#pragma unroll
        for (int j = 0; j < 2; ++j)
          gload_lds16(src + j * 512, dst + (wave * 2 + j) * 512);
      }

      // 8 MFMAs: this wave's M-half against its B fragment
      const unsigned short* wbuf = wl[t & 1] + (wm * 8) * 512 + lane * 8;
#pragma unroll
      for (int j = 0; j < 8; ++j) {
        bf16x8 av = *(const bf16x8*)(wbuf + j * 512);
        acc[j] = __builtin_amdgcn_mfma_f32_16x16x32_bf16(av, bv, acc[j], 0, 0, 0);
      }
    }
  }

  // ---- epilogue: bias + SiLU.  C/D: col(px)=lane&15, row=kg*4+r
#pragma unroll
  for (int j = 0; j < 8; ++j) {
    int cob = (wm * 8 + j) * 16 + (kg << 2);
#pragma unroll
    for (int r = 0; r < 4; ++r) {
      float y = acc[j][r] + bias[cob + r];
      out[(((size_t)(b * C_OUT + cob + r)) << 12) + (h << 6) + px] =
          y / (1.f + expf(-y));
    }
  }
}

// ---------------------------------------------------------------------------
extern "C" void kernel_launch(void* const* d_in, const int* in_sizes, int n_in,
                              void* d_out, int out_size, void* d_ws, size_t ws_size,
                              hipStream_t stream) {
  const float* feat_arm = (const float*)d_in[0];
  const float* feat_up  = (const float*)d_in[1];
  const float* off_w    = (const float*)d_in[2];
  const float* off_b    = (const float*)d_in[3];
  const float* dcn_w    = (const float*)d_in[4];
  const float* dcn_b    = (const float*)d_in[5];
  float* out = (float*)d_out;

  float* ws = (float*)d_ws;
  float* offbuf = ws;                                        // OFF_ELEMS f32
  unsigned short* wo = (unsigned short*)(ws + OFF_ELEMS);    // WOFF_PACK bf16
  unsigned short* wd = wo + WOFF_PACK;                       // WDCN_PACK bf16

  pack_w<<<(WDCN_PACK + 255) / 256, 256, 0, stream>>>(off_w, dcn_w, wo, wd);
  offs_conv_mfma<<<BN * 32, 256, 0, stream>>>(feat_arm, feat_up, wo, off_b, offbuf);
  dcn_mfma<<<BN * 64, 512, 0, stream>>>(feat_up, offbuf, wd, dcn_b, out);
}

// Round 11
// 298.071 us; speedup vs baseline: 1.5332x; 1.2256x over previous
//
#include <hip/hip_runtime.h>
#include <math.h>

// feat_arm/feat_up: [16,144,64,64] f32
// off_w: [144,288,3,3], off_b: [144]
// dcn_w: [256,144,3,3], dcn_b: [256]
// out: [16,256,64,64] f32 (silu)
constexpr int BN = 16;
constexpr int C_IN = 144, C_CAT = 288, C_OFF = 144, C_OUT = 256;
constexpr int OFFG = 8, CG = 18;

constexpr int OFF_ELEMS = BN * C_OFF * 64 * 64;   // fp32 offsets in ws
constexpr int WOFF_PACK = 9 * 9 * 9 * 512;        // 373248 bf16 (cb,tap,mtile,lane,i)
constexpr int WDCN_PACK = 8 * 6 * 16 * 512;       // 393216 bf16 (t=g*6+ks, mtile, lane, i)

typedef __attribute__((ext_vector_type(8))) short bf16x8;
typedef __attribute__((ext_vector_type(4))) float f32x4;

__device__ __forceinline__ unsigned short f2bf(float f) {
  unsigned u = __builtin_bit_cast(unsigned, f);
  return (unsigned short)((u + 0x7FFFu + ((u >> 16) & 1u)) >> 16);  // RNE, finite inputs
}

__device__ __forceinline__ unsigned packh2(float a, float b) {
  unsigned short ha = __builtin_bit_cast(unsigned short, (_Float16)a);
  unsigned short hb = __builtin_bit_cast(unsigned short, (_Float16)b);
  return (unsigned)ha | ((unsigned)hb << 16);
}
__device__ __forceinline__ float h2f_lo(unsigned u) {
  return (float)__builtin_bit_cast(_Float16, (unsigned short)(u & 0xFFFFu));
}
__device__ __forceinline__ float h2f_hi(unsigned u) {
  return (float)__builtin_bit_cast(_Float16, (unsigned short)(u >> 16));
}

// async global->LDS, 16B per lane, wave-uniform LDS base
__device__ __forceinline__ void gload_lds16(const void* g, void* l) {
  __builtin_amdgcn_global_load_lds(
      (const __attribute__((address_space(1))) unsigned*)g,
      (__attribute__((address_space(3))) unsigned*)l, 16, 0, 0);
}

// ---------------------------------------------------------------------------
// Kernel 1: pack both weight tensors into MFMA A-fragment order (bf16).
// (round-3 proven version)
// ---------------------------------------------------------------------------
__global__ __launch_bounds__(256) void pack_w(
    const float* __restrict__ off_w, const float* __restrict__ dcn_w,
    unsigned short* __restrict__ wo, unsigned short* __restrict__ wd) {
  int idx = blockIdx.x * 256 + threadIdx.x;
  if (idx < WOFF_PACK) {
    int i = idx & 7, lane = (idx >> 3) & 63, t = idx >> 9;
    int mt = t % 9; t /= 9;
    int tap = t % 9, cb = t / 9;
    int co = mt * 16 + (lane & 15);
    int ci = cb * 32 + ((lane >> 4) << 3) + i;
    wo[idx] = f2bf(off_w[(co * C_CAT + ci) * 9 + tap]);
  }
  if (idx < WDCN_PACK) {
    int i = idx & 7, lane = (idx >> 3) & 63, t = idx >> 9;
    int mt = t & 15; t >>= 4;
    int ks = t % 6, g = t / 6;
    int co = mt * 16 + (lane & 15);
    int r = ks * 32 + ((lane >> 4) << 3) + i;
    float v = 0.f;
    if (r < 162) {
      int ci = r / 9, tap = r - ci * 9;
      v = dcn_w[(co * C_IN + g * CG + ci) * 9 + tap];
    }
    wd[idx] = f2bf(v);
  }
}

// ---------------------------------------------------------------------------
// Kernel 2: offset conv via MFMA (9 shifted GEMMs). Identical to round 3.
// ---------------------------------------------------------------------------
__global__ __launch_bounds__(256) void offs_conv_mfma(
    const float* __restrict__ fa, const float* __restrict__ fu,
    const unsigned short* __restrict__ wt, const float* __restrict__ bias,
    float* __restrict__ out) {
  const int b = blockIdx.x >> 5;
  const int y0 = (blockIdx.x & 31) << 1;
  const int tid = threadIdx.x;
  const int wave = tid >> 6, lane = tid & 63;
  const int kg = lane >> 4, ln = lane & 15;

  __shared__ __align__(16) unsigned short xs[4 * 66 * 32];

  f32x4 acc[9][2];
#pragma unroll
  for (int m = 0; m < 9; ++m)
#pragma unroll
    for (int n = 0; n < 2; ++n) acc[m][n] = {0.f, 0.f, 0.f, 0.f};

  for (int cb = 0; cb < 9; ++cb) {
    __syncthreads();
    for (int idx = tid; idx < 2112; idx += 256) {
      int q = idx / 264;
      int rem = idx - q * 264;
      int row = rem / 66;
      int cc = rem - row * 66;
      int y = y0 - 1 + row, x = cc - 1;
      ushort4 wv = make_ushort4(0, 0, 0, 0);
      if (y >= 0 && y < 64 && x >= 0 && x < 64) {
        int cib = cb * 32 + (q << 2);
        const float* p = (cib < C_IN)
                             ? fa + (((size_t)(b * C_IN + cib)) << 12)
                             : fu + (((size_t)(b * C_IN + cib - C_IN)) << 12);
        int o = (y << 6) + x;
        wv.x = f2bf(p[o]);
        wv.y = f2bf(p[o + 4096]);
        wv.z = f2bf(p[o + 8192]);
        wv.w = f2bf(p[o + 12288]);
      }
      int e = ((row * 66 + cc) << 5) + (((q >> 1) ^ (cc & 3)) << 3) + ((q & 1) << 2);
      *(ushort4*)&xs[e] = wv;
    }
    __syncthreads();

    for (int tap = 0; tap < 9; ++tap) {
      const int ky = tap / 3, kx = tap - ky * 3;
      bf16x8 a[9];
      const unsigned short* wp = wt + (((size_t)(cb * 9 + tap) * 9) << 9) + (lane << 3);
#pragma unroll
      for (int m = 0; m < 9; ++m) a[m] = *(const bf16x8*)(wp + (m << 9));
#pragma unroll
      for (int n = 0; n < 2; ++n) {
        int px = ((wave << 1) + n) * 16 + ln;
        int row = (px >> 6) + ky, cc = (px & 63) + kx;
        int e = ((row * 66 + cc) << 5) + ((kg ^ (cc & 3)) << 3);
        bf16x8 bv = *(const bf16x8*)&xs[e];
#pragma unroll
        for (int m = 0; m < 9; ++m)
          acc[m][n] = __builtin_amdgcn_mfma_f32_16x16x32_bf16(a[m], bv, acc[m][n], 0, 0, 0);
      }
    }
  }

#pragma unroll
  for (int n = 0; n < 2; ++n) {
    int px = ((wave << 1) + n) * 16 + ln;
    int y = y0 + (px >> 6), x = px & 63;
#pragma unroll
    for (int m = 0; m < 9; ++m) {
      int cob = m * 16 + (kg << 2);
#pragma unroll
      for (int r = 0; r < 4; ++r)
        out[(((size_t)(b * C_OFF + cob + r)) << 12) + (y << 6) + x] =
            acc[m][n][r] + bias[cob + r];
    }
  }
}

// ---------------------------------------------------------------------------
// Kernel 3: deformable conv via MFMA. Round-10 skeleton (512 thr, 8 waves =
// 2M x 4N, tap-in-register geometry, colsT[px][200], LDS dbuf A, per-K-step
// barrier). TWO changes:
//  1) x-corner PAIR fusion: the two x-corners are 4B apart -> one 8B load
//     per y-row (2 loads per (ci,tap) instead of 4). Exact x-fold of fx /
//     validity into (wlo,whi) over positions (xL, xL+1), xL=clamp(x0,0,62);
//     borders x0==-1 / x0==63 remapped at geo time. Halves gather instrs
//     AND TA line-serialization work.
//  2) every wave computes tap-8 geometry redundantly in registers (removes
//     geo8 LDS + one barrier per group).
// ---------------------------------------------------------------------------
__global__ __launch_bounds__(512, 4) void dcn_mfma(
    const float* __restrict__ fu, const float* __restrict__ off,
    const unsigned short* __restrict__ wt, const float* __restrict__ bias,
    float* __restrict__ out) {
  const int b = blockIdx.x >> 6, h = blockIdx.x & 63;
  const int tid = threadIdx.x;
  const int wave = tid >> 6, lane = tid & 63;
  const int kg = lane >> 4, ln = lane & 15;
  const int wm = wave >> 2, wn = wave & 3;   // M-half, N-tile
  const int px = (wn << 4) + ln;             // this wave's pixel (n index)

  __shared__ __align__(16) unsigned short colsT[64 * 200];// [px][r pad 200], 25.6KB
  __shared__ __align__(16) unsigned short wl[2][8192];    // A dbuf, 2x16KB

  f32x4 acc[8];
#pragma unroll
  for (int m = 0; m < 8; ++m) acc[m] = {0.f, 0.f, 0.f, 0.f};

  // zero K-pad columns r in [162,200) once (gather never writes them)
  for (int i = tid; i < 64 * 19; i += 512) {
    int p = i / 19, d = i - p * 19;
    *(unsigned*)&colsT[p * 200 + 162 + 2 * d] = 0u;
  }

  // prologue: stage A chunk t=0 into buffer 0 (16 rows of 1KB, 2 per wave)
  {
    const unsigned short* src = wt + (wave * 2) * 512 + lane * 8;
#pragma unroll
    for (int j = 0; j < 2; ++j)
      gload_lds16(src + j * 512, &wl[0][(wave * 2 + j) * 512]);
  }

  // geometry for (group, tap, pixel p), x-corner-pair folded:
  //   gg.x = iL0 | iL1<<16  (row offsets of the 8B pair, xL = clamp(x0,0,62))
  //   gg.z = (wl0, wh0) fp16: weights for row y0's (lo,hi) values
  //   gg.w = (wl1, wh1) fp16: weights for row y0+1
  auto make_geo = [&](int gg_, int tap, int p) -> uint4 {
    int ky = tap / 3, kx = tap - ky * 3;
    int ch = (gg_ * 9 + tap) * 2;
    float oy = off[(((size_t)(b * C_OFF + ch)) << 12) + (h << 6) + p];
    float ox = off[(((size_t)(b * C_OFF + ch + 1)) << 12) + (h << 6) + p];
    float py = (float)(h - 1 + ky) + oy;
    float pxs = (float)(p - 1 + kx) + ox;
    float y0f = floorf(py), x0f = floorf(pxs);
    int y0 = (int)y0f, x0 = (int)x0f;
    float fy = py - y0f, fx = pxs - x0f;
    float vy0 = (y0 >= 0 && y0 < 64) ? 1.f : 0.f;
    float vy1 = (y0 + 1 >= 0 && y0 + 1 < 64) ? 1.f : 0.f;
    float vx0 = (x0 >= 0 && x0 < 64) ? 1.f : 0.f;
    float vx1 = (x0 + 1 >= 0 && x0 + 1 < 64) ? 1.f : 0.f;
    float a0 = (1.f - fx) * vx0;    // weight of value at xc0
    float a1 = fx * vx1;            // weight of value at xc1
    // fold onto loaded pair (xL, xL+1): borders remap (see round-11 notes)
    float wlo = (x0 == -1) ? a1 : (x0 == 63 ? 0.f : a0);
    float whi = (x0 == 63) ? a0 : (x0 == -1 ? 0.f : a1);
    int xL = min(max(x0, 0), 62);
    int yc0 = min(max(y0, 0), 63), yc1 = min(max(y0 + 1, 0), 63);
    float cy0 = (1.f - fy) * vy0, cy1 = fy * vy1;
    uint4 r;
    r.x = (unsigned)((yc0 << 6) + xL) | ((unsigned)((yc1 << 6) + xL) << 16);
    r.y = 0u;
    r.z = packh2(cy0 * wlo, cy0 * whi);
    r.w = packh2(cy1 * wlo, cy1 * whi);
    return r;
  };

  int t = 0;
  for (int g = 0; g < OFFG; ++g) {
    __syncthreads();  // prev group's colsT readers done

    // ---- phase 1: wave w computes tap-w AND tap-8 geometry in registers
    uint4 gg = make_geo(g, wave, lane);
    uint4 g8 = make_geo(g, 8, lane);

    // ---- phase 2: gather, tap-outer (regs) / ci-inner (batch-6, 8B pairs)
    const float* gbase = fu + (((size_t)(b * C_IN + g * CG)) << 12);
    {
      const int iL0 = gg.x & 0xFFFFu, iL1 = gg.x >> 16;
      const float wl0 = h2f_lo(gg.z), wh0 = h2f_hi(gg.z);
      const float wl1 = h2f_lo(gg.w), wh1 = h2f_hi(gg.w);
      for (int cb = 0; cb < 18; cb += 6) {
        float2 v0[6], v1[6];
#pragma unroll
        for (int u = 0; u < 6; ++u) {
          const float* pl = gbase + ((size_t)(cb + u) << 12);
          __builtin_memcpy(&v0[u], pl + iL0, 8);
          __builtin_memcpy(&v1[u], pl + iL1, 8);
        }
#pragma unroll
        for (int u = 0; u < 6; ++u) {
          float s = wl0 * v0[u].x + wh0 * v0[u].y + wl1 * v1[u].x + wh1 * v1[u].y;
          colsT[lane * 200 + (cb + u) * 9 + wave] = f2bf(s);
        }
      }
      // tap 8 rows: ci8 = wave + 8*j (waves 0,1 -> 3 rows; waves 2..7 -> 2)
      const int j0 = g8.x & 0xFFFFu, j1 = g8.x >> 16;
      const float ul0 = h2f_lo(g8.z), uh0 = h2f_hi(g8.z);
      const float ul1 = h2f_lo(g8.w), uh1 = h2f_hi(g8.w);
      const int n8 = (wave < 2) ? 3 : 2;
      float2 w0[3], w1[3];
#pragma unroll
      for (int u = 0; u < 3; ++u) {
        if (u < n8) {
          const float* pl = gbase + ((size_t)(wave + 8 * u) << 12);
          __builtin_memcpy(&w0[u], pl + j0, 8);
          __builtin_memcpy(&w1[u], pl + j1, 8);
        }
      }
#pragma unroll
      for (int u = 0; u < 3; ++u) {
        if (u < n8) {
          float s = ul0 * w0[u].x + uh0 * w0[u].y + ul1 * w1[u].x + uh1 * w1[u].y;
          colsT[lane * 200 + (wave + 8 * u) * 9 + 8] = f2bf(s);
        }
      }
    }
    __syncthreads();

    // ---- phase 3: 6 MFMA K-steps over this group's 192 (padded) k
    for (int ks = 0; ks < 6; ++ks, ++t) {
      // B fragment: ONE ds_read_b128 (colsT row-contiguous, 16B aligned)
      bf16x8 bv = *(const bf16x8*)&colsT[px * 200 + ks * 32 + (kg << 3)];

      __syncthreads();  // stage(t) drained (vmcnt0); prev buf readers done

      // issue stage(t+1) into the other buffer (2 rows per wave)
      if (t < 47) {
        const unsigned short* src =
            wt + (size_t)(t + 1) * 8192 + (wave * 2) * 512 + lane * 8;
        unsigned short* dst = wl[(t + 1) & 1];
#pragma unroll
        for (int j = 0; j < 2; ++j)
          gload_lds16(src + j * 512, dst + (wave * 2 + j) * 512);
      }

      // 8 MFMAs: this wave's M-half against its B fragment
      const unsigned short* wbuf = wl[t & 1] + (wm * 8) * 512 + lane * 8;
#pragma unroll
      for (int j = 0; j < 8; ++j) {
        bf16x8 av = *(const bf16x8*)(wbuf + j * 512);
        acc[j] = __builtin_amdgcn_mfma_f32_16x16x32_bf16(av, bv, acc[j], 0, 0, 0);
      }
    }
  }

  // ---- epilogue: bias + SiLU.  C/D: col(px)=lane&15, row=kg*4+r
#pragma unroll
  for (int j = 0; j < 8; ++j) {
    int cob = (wm * 8 + j) * 16 + (kg << 2);
#pragma unroll
    for (int r = 0; r < 4; ++r) {
      float y = acc[j][r] + bias[cob + r];
      out[(((size_t)(b * C_OUT + cob + r)) << 12) + (h << 6) + px] =
          y / (1.f + expf(-y));
    }
  }
}

// ---------------------------------------------------------------------------
extern "C" void kernel_launch(void* const* d_in, const int* in_sizes, int n_in,
                              void* d_out, int out_size, void* d_ws, size_t ws_size,
                              hipStream_t stream) {
  const float* feat_arm = (const float*)d_in[0];
  const float* feat_up  = (const float*)d_in[1];
  const float* off_w    = (const float*)d_in[2];
  const float* off_b    = (const float*)d_in[3];
  const float* dcn_w    = (const float*)d_in[4];
  const float* dcn_b    = (const float*)d_in[5];
  float* out = (float*)d_out;

  float* ws = (float*)d_ws;
  float* offbuf = ws;                                        // OFF_ELEMS f32
  unsigned short* wo = (unsigned short*)(ws + OFF_ELEMS);    // WOFF_PACK bf16
  unsigned short* wd = wo + WOFF_PACK;                       // WDCN_PACK bf16

  pack_w<<<(WDCN_PACK + 255) / 256, 256, 0, stream>>>(off_w, dcn_w, wo, wd);
  offs_conv_mfma<<<BN * 32, 256, 0, stream>>>(feat_arm, feat_up, wo, off_b, offbuf);
  dcn_mfma<<<BN * 64, 512, 0, stream>>>(feat_up, offbuf, wd, dcn_b, out);
}

// Round 12
// 269.335 us; speedup vs baseline: 1.6968x; 1.1067x over previous
//
#include <hip/hip_runtime.h>
#include <math.h>

// feat_arm/feat_up: [16,144,64,64] f32
// off_w: [144,288,3,3], off_b: [144]
// dcn_w: [256,144,3,3], dcn_b: [256]
// out: [16,256,64,64] f32 (silu)
constexpr int BN = 16;
constexpr int C_IN = 144, C_CAT = 288, C_OFF = 144, C_OUT = 256;
constexpr int OFFG = 8, CG = 18;

constexpr int FUB_ELEMS  = C_IN * BN * 4096;      // 9,437,184 bf16 planar feat_up
constexpr int OFFP_ELEMS = BN * 72 * 4096;        // 4,718,592 u32 fp16 offset pairs
constexpr int WOFF_PACK = 9 * 9 * 9 * 512;        // bf16 (cb,tap,mtile,lane,i)
constexpr int WDCN_PACK = 8 * 6 * 16 * 512;       // bf16 (t=g*6+ks, mtile, lane, i)

typedef __attribute__((ext_vector_type(8))) short bf16x8;
typedef __attribute__((ext_vector_type(4))) float f32x4;
typedef __attribute__((ext_vector_type(2))) _Float16 f16x2;
typedef __attribute__((ext_vector_type(4))) unsigned u32x4;

__device__ __forceinline__ unsigned short f2bf(float f) {
  unsigned u = __builtin_bit_cast(unsigned, f);
  return (unsigned short)((u + 0x7FFFu + ((u >> 16) & 1u)) >> 16);  // RNE, finite inputs
}

__device__ __forceinline__ unsigned packh2(float a, float b) {
  unsigned short ha = __builtin_bit_cast(unsigned short, (_Float16)a);
  unsigned short hb = __builtin_bit_cast(unsigned short, (_Float16)b);
  return (unsigned)ha | ((unsigned)hb << 16);
}
__device__ __forceinline__ float h2f_lo(unsigned u) {
  return (float)__builtin_bit_cast(_Float16, (unsigned short)(u & 0xFFFFu));
}
__device__ __forceinline__ float h2f_hi(unsigned u) {
  return (float)__builtin_bit_cast(_Float16, (unsigned short)(u >> 16));
}
__device__ __forceinline__ float bf_lo(unsigned u) {
  return __builtin_bit_cast(float, u << 16);
}
__device__ __forceinline__ float bf_hi(unsigned u) {
  return __builtin_bit_cast(float, u & 0xFFFF0000u);
}

// async global->LDS, 16B per lane, wave-uniform LDS base
__device__ __forceinline__ void gload_lds16(const void* g, void* l) {
  __builtin_amdgcn_global_load_lds(
      (const __attribute__((address_space(1))) unsigned*)g,
      (__attribute__((address_space(3))) unsigned*)l, 16, 0, 0);
}

// ---------------------------------------------------------------------------
// Kernel 0: feat_up -> planar bf16 copy (halves gather footprint)
// ---------------------------------------------------------------------------
__global__ __launch_bounds__(256) void tobf16_fu(
    const float* __restrict__ fu, unsigned short* __restrict__ fuB) {
  int i = (blockIdx.x * 256 + threadIdx.x) * 4;
  float4 v = *(const float4*)(fu + i);
  ushort4 o;
  o.x = f2bf(v.x); o.y = f2bf(v.y); o.z = f2bf(v.z); o.w = f2bf(v.w);
  *(ushort4*)(fuB + i) = o;
}

// ---------------------------------------------------------------------------
// Kernel 1: pack both weight tensors into MFMA A-fragment order (bf16).
// (round-3 proven version)
// ---------------------------------------------------------------------------
__global__ __launch_bounds__(256) void pack_w(
    const float* __restrict__ off_w, const float* __restrict__ dcn_w,
    unsigned short* __restrict__ wo, unsigned short* __restrict__ wd) {
  int idx = blockIdx.x * 256 + threadIdx.x;
  if (idx < WOFF_PACK) {
    int i = idx & 7, lane = (idx >> 3) & 63, t = idx >> 9;
    int mt = t % 9; t /= 9;
    int tap = t % 9, cb = t / 9;
    int co = mt * 16 + (lane & 15);
    int ci = cb * 32 + ((lane >> 4) << 3) + i;
    wo[idx] = f2bf(off_w[(co * C_CAT + ci) * 9 + tap]);
  }
  if (idx < WDCN_PACK) {
    int i = idx & 7, lane = (idx >> 3) & 63, t = idx >> 9;
    int mt = t & 15; t >>= 4;
    int ks = t % 6, g = t / 6;
    int co = mt * 16 + (lane & 15);
    int r = ks * 32 + ((lane >> 4) << 3) + i;
    float v = 0.f;
    if (r < 162) {
      int ci = r / 9, tap = r - ci * 9;
      v = dcn_w[(co * C_IN + g * CG + ci) * 9 + tap];
    }
    wd[idx] = f2bf(v);
  }
}

// ---------------------------------------------------------------------------
// Kernel 2: offset conv via MFMA (9 shifted GEMMs). r3-proven; epilogue now
// packs (oy,ox) channel pairs as fp16x2 in one u32: offp[b][72][h][w].
// ---------------------------------------------------------------------------
__global__ __launch_bounds__(256) void offs_conv_mfma(
    const float* __restrict__ fa, const float* __restrict__ fu,
    const unsigned short* __restrict__ wt, const float* __restrict__ bias,
    unsigned* __restrict__ offp) {
  const int b = blockIdx.x >> 5;
  const int y0 = (blockIdx.x & 31) << 1;
  const int tid = threadIdx.x;
  const int wave = tid >> 6, lane = tid & 63;
  const int kg = lane >> 4, ln = lane & 15;

  __shared__ __align__(16) unsigned short xs[4 * 66 * 32];

  f32x4 acc[9][2];
#pragma unroll
  for (int m = 0; m < 9; ++m)
#pragma unroll
    for (int n = 0; n < 2; ++n) acc[m][n] = {0.f, 0.f, 0.f, 0.f};

  for (int cb = 0; cb < 9; ++cb) {
    __syncthreads();
    for (int idx = tid; idx < 2112; idx += 256) {
      int q = idx / 264;
      int rem = idx - q * 264;
      int row = rem / 66;
      int cc = rem - row * 66;
      int y = y0 - 1 + row, x = cc - 1;
      ushort4 wv = make_ushort4(0, 0, 0, 0);
      if (y >= 0 && y < 64 && x >= 0 && x < 64) {
        int cib = cb * 32 + (q << 2);
        const float* p = (cib < C_IN)
                             ? fa + (((size_t)(b * C_IN + cib)) << 12)
                             : fu + (((size_t)(b * C_IN + cib - C_IN)) << 12);
        int o = (y << 6) + x;
        wv.x = f2bf(p[o]);
        wv.y = f2bf(p[o + 4096]);
        wv.z = f2bf(p[o + 8192]);
        wv.w = f2bf(p[o + 12288]);
      }
      int e = ((row * 66 + cc) << 5) + (((q >> 1) ^ (cc & 3)) << 3) + ((q & 1) << 2);
      *(ushort4*)&xs[e] = wv;
    }
    __syncthreads();

    for (int tap = 0; tap < 9; ++tap) {
      const int ky = tap / 3, kx = tap - ky * 3;
      bf16x8 a[9];
      const unsigned short* wp = wt + (((size_t)(cb * 9 + tap) * 9) << 9) + (lane << 3);
#pragma unroll
      for (int m = 0; m < 9; ++m) a[m] = *(const bf16x8*)(wp + (m << 9));
#pragma unroll
      for (int n = 0; n < 2; ++n) {
        int px = ((wave << 1) + n) * 16 + ln;
        int row = (px >> 6) + ky, cc = (px & 63) + kx;
        int e = ((row * 66 + cc) << 5) + ((kg ^ (cc & 3)) << 3);
        bf16x8 bv = *(const bf16x8*)&xs[e];
#pragma unroll
        for (int m = 0; m < 9; ++m)
          acc[m][n] = __builtin_amdgcn_mfma_f32_16x16x32_bf16(a[m], bv, acc[m][n], 0, 0, 0);
      }
    }
  }

  // epilogue: C/D col=lane&15 (px), row=(lane>>4)*4+r (co); pack pairs fp16
#pragma unroll
  for (int n = 0; n < 2; ++n) {
    int px = ((wave << 1) + n) * 16 + ln;
    int y = y0 + (px >> 6), x = px & 63;
#pragma unroll
    for (int m = 0; m < 9; ++m) {
      int cob = m * 16 + (kg << 2);
#pragma unroll
      for (int rr = 0; rr < 4; rr += 2) {
        unsigned v = packh2(acc[m][n][rr] + bias[cob + rr],
                            acc[m][n][rr + 1] + bias[cob + rr + 1]);
        offp[(((size_t)(b * 72 + ((cob + rr) >> 1))) << 12) + (y << 6) + x] = v;
      }
    }
  }
}

// ---------------------------------------------------------------------------
// Kernel 3: deformable conv via MFMA. Round-11 skeleton (512 thr, 8 waves =
// 2M x 4N, tap-in-register geometry, x-pair fold, LDS dbuf A, per-K-step
// barrier). Changes:
//  1) features sampled from PLANAR BF16 fuB: x-pair = 4B (memcpy, any
//     alignment) -> gather footprint halved (~7 lines/instr vs ~13).
//  2) offsets read as packed fp16 pairs (one u32 per (tap,px)).
//  3) colsT row stride 202 ushort (odd dword count) -> scalar writes
//     conflict-free (was 8-way, 9.6M); B-frag read = 4 x ds_read_b32.
// ---------------------------------------------------------------------------
__global__ __launch_bounds__(512, 4) void dcn_mfma(
    const unsigned short* __restrict__ fuB, const unsigned* __restrict__ offp,
    const unsigned short* __restrict__ wt, const float* __restrict__ bias,
    float* __restrict__ out) {
  const int b = blockIdx.x >> 6, h = blockIdx.x & 63;
  const int tid = threadIdx.x;
  const int wave = tid >> 6, lane = tid & 63;
  const int kg = lane >> 4, ln = lane & 15;
  const int wm = wave >> 2, wn = wave & 3;   // M-half, N-tile
  const int px = (wn << 4) + ln;             // this wave's pixel (n index)

  __shared__ __align__(16) unsigned short colsT[64 * 202];// [px][r pad 202], 25.9KB
  __shared__ __align__(16) unsigned short wl[2][8192];    // A dbuf, 2x16KB

  f32x4 acc[8];
#pragma unroll
  for (int m = 0; m < 8; ++m) acc[m] = {0.f, 0.f, 0.f, 0.f};

  // zero K-pad region r in [162,192) once (15 u32 per px)
  for (int i = tid; i < 64 * 15; i += 512) {
    int p = i / 15, d = i - p * 15;
    *(unsigned*)&colsT[p * 202 + 162 + 2 * d] = 0u;
  }

  // prologue: stage A chunk t=0 into buffer 0 (16 rows of 1KB, 2 per wave)
  {
    const unsigned short* src = wt + (wave * 2) * 512 + lane * 8;
#pragma unroll
    for (int j = 0; j < 2; ++j)
      gload_lds16(src + j * 512, &wl[0][(wave * 2 + j) * 512]);
  }

  // geometry for (group, tap, pixel p), x-corner-pair folded (r11-proven):
  //   gg.x = iL0 | iL1<<16  (element offsets of the pair rows, xL=clamp(x0,0,62))
  //   gg.z = (wl0, wh0) fp16, gg.w = (wl1, wh1) fp16
  auto make_geo = [&](int gg_, int tap, int p) -> uint4 {
    int ky = tap / 3, kx = tap - ky * 3;
    unsigned op = offp[(((size_t)(b * 72 + gg_ * 9 + tap)) << 12) + (h << 6) + p];
    float oy = h2f_lo(op), ox = h2f_hi(op);
    float py = (float)(h - 1 + ky) + oy;
    float pxs = (float)(p - 1 + kx) + ox;
    float y0f = floorf(py), x0f = floorf(pxs);
    int y0 = (int)y0f, x0 = (int)x0f;
    float fy = py - y0f, fx = pxs - x0f;
    float vy0 = (y0 >= 0 && y0 < 64) ? 1.f : 0.f;
    float vy1 = (y0 + 1 >= 0 && y0 + 1 < 64) ? 1.f : 0.f;
    float vx0 = (x0 >= 0 && x0 < 64) ? 1.f : 0.f;
    float vx1 = (x0 + 1 >= 0 && x0 + 1 < 64) ? 1.f : 0.f;
    float a0 = (1.f - fx) * vx0;
    float a1 = fx * vx1;
    float wlo = (x0 == -1) ? a1 : (x0 == 63 ? 0.f : a0);
    float whi = (x0 == 63) ? a0 : (x0 == -1 ? 0.f : a1);
    int xL = min(max(x0, 0), 62);
    int yc0 = min(max(y0, 0), 63), yc1 = min(max(y0 + 1, 0), 63);
    float cy0 = (1.f - fy) * vy0, cy1 = fy * vy1;
    uint4 r;
    r.x = (unsigned)((yc0 << 6) + xL) | ((unsigned)((yc1 << 6) + xL) << 16);
    r.y = 0u;
    r.z = packh2(cy0 * wlo, cy0 * whi);
    r.w = packh2(cy1 * wlo, cy1 * whi);
    return r;
  };

  int t = 0;
  for (int g = 0; g < OFFG; ++g) {
    __syncthreads();  // prev group's colsT readers done

    // ---- phase 1: wave w computes tap-w AND tap-8 geometry in registers
    uint4 gg = make_geo(g, wave, lane);
    uint4 g8 = make_geo(g, 8, lane);

    // ---- phase 2: gather from bf16 planar, tap-outer / ci-inner (batch-6)
    const unsigned short* gbase = fuB + (((size_t)(b * C_IN + g * CG)) << 12);
    {
      const int iL0 = gg.x & 0xFFFFu, iL1 = gg.x >> 16;
      const float wl0 = h2f_lo(gg.z), wh0 = h2f_hi(gg.z);
      const float wl1 = h2f_lo(gg.w), wh1 = h2f_hi(gg.w);
      for (int cb = 0; cb < 18; cb += 6) {
        unsigned d0[6], d1[6];
#pragma unroll
        for (int u = 0; u < 6; ++u) {
          const unsigned short* pl = gbase + ((size_t)(cb + u) << 12);
          __builtin_memcpy(&d0[u], pl + iL0, 4);   // bf16 pair (xL, xL+1)
          __builtin_memcpy(&d1[u], pl + iL1, 4);
        }
#pragma unroll
        for (int u = 0; u < 6; ++u) {
          float s = wl0 * bf_lo(d0[u]) + wh0 * bf_hi(d0[u]) +
                    wl1 * bf_lo(d1[u]) + wh1 * bf_hi(d1[u]);
          colsT[lane * 202 + (cb + u) * 9 + wave] = f2bf(s);
        }
      }
      // tap 8 rows: ci8 = wave + 8*j (waves 0,1 -> 3 rows; waves 2..7 -> 2)
      const int j0 = g8.x & 0xFFFFu, j1 = g8.x >> 16;
      const float ul0 = h2f_lo(g8.z), uh0 = h2f_hi(g8.z);
      const float ul1 = h2f_lo(g8.w), uh1 = h2f_hi(g8.w);
      const int n8 = (wave < 2) ? 3 : 2;
      unsigned e0[3], e1[3];
#pragma unroll
      for (int u = 0; u < 3; ++u) {
        if (u < n8) {
          const unsigned short* pl = gbase + ((size_t)(wave + 8 * u) << 12);
          __builtin_memcpy(&e0[u], pl + j0, 4);
          __builtin_memcpy(&e1[u], pl + j1, 4);
        }
      }
#pragma unroll
      for (int u = 0; u < 3; ++u) {
        if (u < n8) {
          float s = ul0 * bf_lo(e0[u]) + uh0 * bf_hi(e0[u]) +
                    ul1 * bf_lo(e1[u]) + uh1 * bf_hi(e1[u]);
          colsT[lane * 202 + (wave + 8 * u) * 9 + 8] = f2bf(s);
        }
      }
    }
    __syncthreads();

    // ---- phase 3: 6 MFMA K-steps over this group's 192 (padded) k
    for (int ks = 0; ks < 6; ++ks, ++t) {
      // B fragment: 4 x ds_read_b32 (odd-dword row stride, conflict-free)
      int cbase = px * 202 + ks * 32 + (kg << 3);
      u32x4 bu;
      bu[0] = *(const unsigned*)&colsT[cbase];
      bu[1] = *(const unsigned*)&colsT[cbase + 2];
      bu[2] = *(const unsigned*)&colsT[cbase + 4];
      bu[3] = *(const unsigned*)&colsT[cbase + 6];
      bf16x8 bv = __builtin_bit_cast(bf16x8, bu);

      __syncthreads();  // stage(t) drained (vmcnt0); prev buf readers done

      // issue stage(t+1) into the other buffer (2 rows per wave)
      if (t < 47) {
        const unsigned short* src =
            wt + (size_t)(t + 1) * 8192 + (wave * 2) * 512 + lane * 8;
        unsigned short* dst = wl[(t + 1) & 1];
#pragma unroll
        for (int j = 0; j < 2; ++j)
          gload_lds16(src + j * 512, dst + (wave * 2 + j) * 512);
      }

      // 8 MFMAs: this wave's M-half against its B fragment
      const unsigned short* wbuf = wl[t & 1] + (wm * 8) * 512 + lane * 8;
#pragma unroll
      for (int j = 0; j < 8; ++j) {
        bf16x8 av = *(const bf16x8*)(wbuf + j * 512);
        acc[j] = __builtin_amdgcn_mfma_f32_16x16x32_bf16(av, bv, acc[j], 0, 0, 0);
      }
    }
  }

  // ---- epilogue: bias + SiLU.  C/D: col(px)=lane&15, row=kg*4+r
#pragma unroll
  for (int j = 0; j < 8; ++j) {
    int cob = (wm * 8 + j) * 16 + (kg << 2);
#pragma unroll
    for (int r = 0; r < 4; ++r) {
      float y = acc[j][r] + bias[cob + r];
      out[(((size_t)(b * C_OUT + cob + r)) << 12) + (h << 6) + px] =
          y / (1.f + expf(-y));
    }
  }
}

// ---------------------------------------------------------------------------
extern "C" void kernel_launch(void* const* d_in, const int* in_sizes, int n_in,
                              void* d_out, int out_size, void* d_ws, size_t ws_size,
                              hipStream_t stream) {
  const float* feat_arm = (const float*)d_in[0];
  const float* feat_up  = (const float*)d_in[1];
  const float* off_w    = (const float*)d_in[2];
  const float* off_b    = (const float*)d_in[3];
  const float* dcn_w    = (const float*)d_in[4];
  const float* dcn_b    = (const float*)d_in[5];
  float* out = (float*)d_out;

  // ws layout (39,281,664 B total — identical footprint to round 11):
  unsigned short* fuB = (unsigned short*)d_ws;            // FUB_ELEMS bf16
  unsigned* offp = (unsigned*)(fuB + FUB_ELEMS);          // OFFP_ELEMS u32
  unsigned short* wo = (unsigned short*)(offp + OFFP_ELEMS);
  unsigned short* wd = wo + WOFF_PACK;

  tobf16_fu<<<FUB_ELEMS / 1024, 256, 0, stream>>>(feat_up, fuB);
  pack_w<<<(WDCN_PACK + 255) / 256, 256, 0, stream>>>(off_w, dcn_w, wo, wd);
  offs_conv_mfma<<<BN * 32, 256, 0, stream>>>(feat_arm, feat_up, wo, off_b, offp);
  dcn_mfma<<<BN * 64, 512, 0, stream>>>(fuB, offp, wd, dcn_b, out);
}